// Round 15
// baseline (357.121 us; speedup 1.0000x reference)
//
#include <hip/hip_runtime.h>
#include <hip/hip_bf16.h>

typedef unsigned short ushort_t;
typedef short short8 __attribute__((ext_vector_type(8)));
typedef unsigned short u16x4 __attribute__((ext_vector_type(4)));
typedef float f32x4 __attribute__((ext_vector_type(4)));
typedef int int2v __attribute__((ext_vector_type(2)));
typedef int int4v __attribute__((ext_vector_type(4)));

#define MFMA_BF16 __builtin_amdgcn_mfma_f32_16x16x32_bf16

// global -> LDS async copy, 16B per lane. LDS base must be wave-uniform.
#define GLDS16(g, l) __builtin_amdgcn_global_load_lds( \
    (__attribute__((address_space(1))) void*)(g), \
    (__attribute__((address_space(3))) void*)(l), 16, 0, 0)

__device__ __forceinline__ unsigned short f2bf(float f) {
  union { float f; unsigned u; } v; v.f = f;
  unsigned r = v.u + 0x7FFFu + ((v.u >> 16) & 1u);
  return (unsigned short)(r >> 16);
}
__device__ __forceinline__ float bf2f(unsigned short h) {
  union { unsigned u; float f; } v; v.u = ((unsigned)h) << 16;
  return v.f;
}
__device__ __forceinline__ unsigned pack_bf2(float a, float b) {
  __hip_bfloat162 t = __float22bfloat162_rn(float2{a, b});
  union { __hip_bfloat162 h; unsigned u; } v; v.h = t;
  return v.u;
}
// raw 2^x (v_exp_f32)
__device__ __forceinline__ float exp2_raw(float x) {
  float r;
  asm volatile("v_exp_f32 %0, %1" : "=v"(r) : "v"(x));
  return r;
}

// ---------------- problem constants ----------------
#define BB 4
#define LL 2048
#define DD 1024
#define HH 16
#define HD 64
#define NROW (BB * LL)        // 8192
#define LOG2E 1.4426950408889634f
#define EPAD 68               // epilogue bounce row stride

// ---------------- weight transpose-convert: W (RxC fp32) -> WT (CxR bf16) ---
// PERM=1 (W1 only): out-row permutation so x1 col j -> 64-block slot [0,32),
// x2 col j -> slot [32,64): silu gate pairs land in the same lane's acc.
template <int PERM>
__global__ __launch_bounds__(256) void wconv(const float* __restrict__ W,
                                             ushort_t* __restrict__ WT,
                                             int R, int C) {
  __shared__ float tile[32][33];
  const int ct = blockIdx.x * 32, rt = blockIdx.y * 32;
  const int tx = threadIdx.x & 31, ty = threadIdx.x >> 5; // ty 0..7
#pragma unroll
  for (int j = 0; j < 4; ++j)
    tile[ty + j * 8][tx] = W[(size_t)(rt + ty + j * 8) * C + ct + tx];
  __syncthreads();
  int orow0 = ct;
  if (PERM)
    orow0 = (ct < 1024) ? ((ct >> 5) * 64) : ((((ct - 1024) >> 5) * 64) + 32);
#pragma unroll
  for (int j = 0; j < 4; ++j)
    WT[(size_t)(orow0 + ty + j * 8) * R + rt + tx] = f2bf(tile[tx][ty + j * 8]);
}

// ---------------- mask pre-scale: maskl = mask * log2e ----------------
__global__ void mask_scale(const float* __restrict__ mask,
                           float* __restrict__ maskl) {
  const int i = blockIdx.x * 256 + threadIdx.x;
  maskl[i] = mask[i] * LOG2E;
}

// ---------------- layernorm: fp32/bf16 in -> bf16 out ----------------
template <int BIN>
__global__ __launch_bounds__(256) void ln_kernel(const void* __restrict__ xin,
                                                 const float* __restrict__ g,
                                                 const float* __restrict__ bt,
                                                 ushort_t* __restrict__ out) {
  const int row = blockIdx.x, t = threadIdx.x;
  f32x4 v;
  if (BIN) {
    const u16x4 hv =
        *(const u16x4*)((const ushort_t*)xin + (size_t)row * DD + t * 4);
    v[0] = bf2f(hv[0]); v[1] = bf2f(hv[1]);
    v[2] = bf2f(hv[2]); v[3] = bf2f(hv[3]);
  } else {
    v = *(const f32x4*)((const float*)xin + (size_t)row * DD + t * 4);
  }
  float s = v[0] + v[1] + v[2] + v[3];
  float sq = v[0] * v[0] + v[1] * v[1] + v[2] * v[2] + v[3] * v[3];
#pragma unroll
  for (int off = 1; off < 64; off <<= 1) {
    s += __shfl_xor(s, off);
    sq += __shfl_xor(sq, off);
  }
  __shared__ float aw[4], aq[4];
  if ((t & 63) == 0) { aw[t >> 6] = s; aq[t >> 6] = sq; }
  __syncthreads();
  s = aw[0] + aw[1] + aw[2] + aw[3];
  sq = aq[0] + aq[1] + aq[2] + aq[3];
  const float mu = s * (1.f / DD);
  const float var = sq * (1.f / DD) - mu * mu;
  const float rs = rsqrtf(var + 1e-5f);
  u16x4 o;
#pragma unroll
  for (int j = 0; j < 4; ++j) {
    const int c = t * 4 + j;
    o[j] = f2bf((v[j] - mu) * rs * g[c] + bt[c]);
  }
  *(u16x4*)(out + (size_t)row * DD + t * 4) = o;
}

// ---------------- unified 128^2 GEMM, BK=64, swizzled LDS ------------------
// 2-D panel-grouped XCD swizzle. Per K-step: stage 16KB A + 16KB B, ONE
// vmcnt(0)+barrier drain, 2 k-half reg passes x 16 MFMA. XOR swizzle
// chunk^=(row&7) both sides.
// EPI 1: QKV -> rope(Q,K) via LDS-bounced vectorized epilogue (Es aliases
//        As/Bs after the loop) + slot-permuted V direct.
// EPI 2: W1 (permuted cols) -> silu(x1)*x2 into gact.
// EPI 3: Wo -> bf16 out = fp32 resid + C.  EPI 4: W2 -> fp32 = bf16 resid + C.
template <int EPI>
__global__ __launch_bounds__(256) void gemm64(
    const ushort_t* __restrict__ A, const ushort_t* __restrict__ BT,
    const float* __restrict__ pcos, const float* __restrict__ psin,
    ushort_t* __restrict__ qh, ushort_t* __restrict__ kh,
    ushort_t* __restrict__ vt, ushort_t* __restrict__ gact,
    ushort_t* __restrict__ Cb, float* __restrict__ Cf,
    const float* __restrict__ residf, const ushort_t* __restrict__ residb,
    int M, int N, int K) {
  __shared__ ushort_t smem[4 * 64 * EPAD];   // 34.8 KB; aliases As|Bs and Es
  ushort_t* As = smem;                        // 128*64
  ushort_t* Bs = smem + 128 * 64;             // 128*64
  const int tid = threadIdx.x;
  const int lane = tid & 63;
  const int w = tid >> 6;             // 0..3
  const int wr = w >> 1, wc = w & 1;
  // 2-D panel-grouped XCD swizzle (bijective: M/128 = 64 = 8 XCD x 8 rows)
  const int orig = blockIdx.y * gridDim.x + blockIdx.x;
  const int xcd = orig & 7;
  const int lid = orig >> 3;
  const int bm = (xcd * 8 + (lid & 7)) * 128;
  const int bn = (lid >> 3) * 128;
  const int fr = lane & 15;
  const int hi = lane >> 4;           // 0..3
  const int srow8 = lane >> 3;                       // 0..7
  const int schunk = (lane & 7) ^ srow8;             // pre-swizzled src chunk
  f32x4 acc[4][4];
#pragma unroll
  for (int m = 0; m < 4; ++m)
#pragma unroll
    for (int n = 0; n < 4; ++n) acc[m][n] = (f32x4){0.f, 0.f, 0.f, 0.f};

  const int nk = K >> 6;
  for (int kt = 0; kt < nk; ++kt) {
    __syncthreads();  // previous step's ds_reads done
#pragma unroll
    for (int c = 0; c < 4; ++c) {
      const int rbase = w * 32 + c * 8;
      const int grow = rbase + srow8;
      GLDS16(A + (size_t)(bm + grow) * K + kt * 64 + schunk * 8,
             &As[rbase * 64]);
      GLDS16(BT + (size_t)(bn + grow) * K + kt * 64 + schunk * 8,
             &Bs[rbase * 64]);
    }
    asm volatile("s_waitcnt vmcnt(0)" ::: "memory");
    __syncthreads();  // staged tile visible
#pragma unroll
    for (int khf = 0; khf < 2; ++khf) {
      short8 af[4], bf_[4];
#pragma unroll
      for (int m = 0; m < 4; ++m) {
        const int r = wr * 64 + m * 16 + fr;
        af[m] = *(const short8*)&As[r * 64 + (((khf << 2) + hi) ^ (fr & 7)) * 8];
      }
#pragma unroll
      for (int n = 0; n < 4; ++n) {
        const int r = wc * 64 + n * 16 + fr;
        bf_[n] = *(const short8*)&Bs[r * 64 + (((khf << 2) + hi) ^ (fr & 7)) * 8];
      }
#pragma unroll
      for (int m = 0; m < 4; ++m)
#pragma unroll
        for (int n = 0; n < 4; ++n)
          acc[m][n] = MFMA_BF16(af[m], bf_[n], acc[m][n], 0, 0, 0);
    }
  }

  if (EPI == 1) {
    const int gcol = bn + wc * 64;       // 0..3071
    const int region = gcol >> 10;       // 0=q, 1=k, 2=v
    const int h = (gcol & 1023) >> 6;
    const int b = bm >> 11;
    __syncthreads();                     // As/Bs dead in ALL waves; Es safe
    if (region < 2) {
      ushort_t* Es = smem + w * 64 * EPAD;
      // dump wave's 64x64 acc tile
#pragma unroll
      for (int m = 0; m < 4; ++m)
#pragma unroll
        for (int n = 0; n < 4; ++n)
#pragma unroll
          for (int r = 0; r < 4; ++r)
            Es[(m * 16 + hi * 4 + r) * EPAD + n * 16 + fr] =
                f2bf(acc[m][n][r]);
      asm volatile("s_waitcnt lgkmcnt(0)" ::: "memory");
      __builtin_amdgcn_sched_barrier(0);
      // lane owns one row: vectorized rope
      const int rl = lane;
      const float qs = (region == 0) ? (0.125f * LOG2E) : 1.0f;
      const int gr = bm + wr * 64 + rl;
      const int l = gr & 2047;
      const float* pc = pcos + (size_t)gr * DD + h * 64;
      const float* ps = psin + (size_t)gr * DD + h * 64;
      ushort_t* dst = ((region == 0) ? qh : kh) +
                      ((size_t)(b * HH + h) * LL + l) * HD;
#pragma unroll
      for (int d0 = 0; d0 < 32; d0 += 8) {
        const u16x4 a0 = *(const u16x4*)&Es[rl * EPAD + d0];
        const u16x4 a1 = *(const u16x4*)&Es[rl * EPAD + d0 + 4];
        const u16x4 b0 = *(const u16x4*)&Es[rl * EPAD + d0 + 32];
        const u16x4 b1 = *(const u16x4*)&Es[rl * EPAD + d0 + 36];
        const f32x4 cl0 = *(const f32x4*)(pc + d0);
        const f32x4 cl1 = *(const f32x4*)(pc + d0 + 4);
        const f32x4 ch0 = *(const f32x4*)(pc + d0 + 32);
        const f32x4 ch1 = *(const f32x4*)(pc + d0 + 36);
        const f32x4 sl0 = *(const f32x4*)(ps + d0);
        const f32x4 sl1 = *(const f32x4*)(ps + d0 + 4);
        const f32x4 sh0 = *(const f32x4*)(ps + d0 + 32);
        const f32x4 sh1 = *(const f32x4*)(ps + d0 + 36);
        short8 olo, ohi;
#pragma unroll
        for (int j = 0; j < 4; ++j) {
          const float xl0 = bf2f(a0[j]), xh0 = bf2f(b0[j]);
          const float xl1 = bf2f(a1[j]), xh1 = bf2f(b1[j]);
          olo[j] = (short)f2bf((xl0 * cl0[j] - xh0 * sl0[j]) * qs);
          olo[j + 4] = (short)f2bf((xl1 * cl1[j] - xh1 * sl1[j]) * qs);
          ohi[j] = (short)f2bf((xh0 * ch0[j] + xl0 * sh0[j]) * qs);
          ohi[j + 4] = (short)f2bf((xh1 * ch1[j] + xl1 * sh1[j]) * qs);
        }
        *(short8*)(dst + d0) = olo;
        *(short8*)(dst + d0 + 32) = ohi;
      }
    } else {
      // V: slot-permuted vt [B*H, HD, L]; key-in-tile = m*16 + 4*hi + r
      const size_t bhv = (size_t)(b * HH + h);
      const int l0 = (bm & 2047) + wr * 64;
      const int lt = l0 >> 6;
#pragma unroll
      for (int m = 0; m < 4; ++m) {
        const int slotb = 32 * (m >> 1) + 8 * hi + 4 * (m & 1);
#pragma unroll
        for (int n = 0; n < 4; ++n) {
          const int hd = n * 16 + fr;
          u16x4 wv;
          wv[0] = f2bf(acc[m][n][0]);
          wv[1] = f2bf(acc[m][n][1]);
          wv[2] = f2bf(acc[m][n][2]);
          wv[3] = f2bf(acc[m][n][3]);
          *(u16x4*)(vt + (bhv * HD + hd) * LL + lt * 64 + slotb) = wv;
        }
      }
    }
  } else if (EPI == 2) {
    // silu gate; wave's 64 permuted cols = 32 gate outputs
    const int jbase = ((bn + wc * 64) >> 6) * 32;
#pragma unroll
    for (int m = 0; m < 4; ++m) {
      const int gr0 = bm + wr * 64 + m * 16 + hi * 4;
#pragma unroll
      for (int r = 0; r < 4; ++r) {
        ushort_t* dst = gact + (size_t)(gr0 + r) * DD + jbase;
#pragma unroll
        for (int n = 0; n < 2; ++n) {
          const float x1 = acc[m][n][r];
          const float x2 = acc[m][n + 2][r];
          dst[n * 16 + fr] = f2bf(x1 / (1.f + __expf(-x1)) * x2);
        }
      }
    }
  } else {
#pragma unroll
    for (int m = 0; m < 4; ++m)
#pragma unroll
      for (int n = 0; n < 4; ++n)
#pragma unroll
        for (int r = 0; r < 4; ++r) {
          const int gr = bm + wr * 64 + m * 16 + hi * 4 + r;
          const int gc = bn + wc * 64 + n * 16 + fr;
          const size_t o = (size_t)gr * N + gc;
          if (EPI == 3) Cb[o] = f2bf(residf[o] + acc[m][n][r]);
          else          Cf[o] = bf2f(residb[o]) + acc[m][n][r];
        }
  }
}

// ---------------- flash attention (swapped QK^T, no-max softmax) -----------
// XCD-affinity remap: all 16 q-blocks of one head run on the SAME XCD
// (consecutively), so that head's 512KB K/V stays L2-resident -> ~2x less
// HBM fetch. KVBLK=128 single-buffer; P = exp2(S) (log2e pre-folded).
__global__ __launch_bounds__(512) void attn_kernel(
    const ushort_t* __restrict__ qh, const ushort_t* __restrict__ kh,
    const ushort_t* __restrict__ vt, const float* __restrict__ maskl,
    ushort_t* __restrict__ ctx) {
  const int tid = threadIdx.x, lane = tid & 63, w = tid >> 6;  // w 0..7
  // XCD-affinity block remap (1024 blocks, 8 XCDs, 64 heads)
  const int flat = blockIdx.y * gridDim.x + blockIdx.x;
  const int xcd = flat & 7;
  const int slot = flat >> 3;              // 0..127
  const int bh = xcd * 8 + (slot >> 4);    // 8 heads per XCD
  const int q0 = (slot & 15) * 128;
  const int b = bh >> 4, h = bh & 15;
  __shared__ ushort_t Ks[2][64 * 64];   // [sub][kk][d], swizzled
  __shared__ ushort_t Vs[2][64 * 64];   // [sub][d][slot], swizzled
  const int fr = lane & 15;
  const int hi = lane >> 4;
  const int fo = hi * 8;
  const int qrow = q0 + w * 16 + fr;
  const size_t qoff = ((size_t)bh * LL + qrow) * HD + fo;
  const short8 qf0 = *(const short8*)(qh + qoff);
  const short8 qf1 = *(const short8*)(qh + qoff + 32);
  short8 ones;
#pragma unroll
  for (int i = 0; i < 8; ++i) ones[i] = (short)0x3F80;  // bf16 1.0

  f32x4 oacc[4];
  f32x4 lacc = (f32x4){0.f, 0.f, 0.f, 0.f};
#pragma unroll
  for (int m = 0; m < 4; ++m) oacc[m] = (f32x4){0.f, 0.f, 0.f, 0.f};

  const int lrow = lane >> 3;                    // row within 8-row seg
  const int lcs = ((lane & 7) ^ lrow) * 8;       // pre-swizzled source col
  const int rr = w * 8 + lrow;                   // 0..63

  const float* mrow = maskl + (size_t)b * LL;

  const int NT = LL / 128;                       // 16 iterations
  for (int kt = 0; kt < NT; ++kt) {
    __syncthreads();   // previous iteration's LDS reads done
    // stage 128 keys: 2 subtiles of K and V (4 loads per wave)
    GLDS16(kh + ((size_t)bh * LL + kt * 128 + rr) * HD + lcs, &Ks[0][w * 512]);
    GLDS16(kh + ((size_t)bh * LL + kt * 128 + 64 + rr) * HD + lcs,
           &Ks[1][w * 512]);
    GLDS16(vt + ((size_t)bh * HD + rr) * LL + kt * 128 + lcs, &Vs[0][w * 512]);
    GLDS16(vt + ((size_t)bh * HD + rr) * LL + kt * 128 + 64 + lcs,
           &Vs[1][w * 512]);
    // this tile's pre-scaled mask (L2-resident broadcast loads)
    f32x4 mk[8];
#pragma unroll
    for (int n = 0; n < 8; ++n)
      mk[n] = *(const f32x4*)(mrow + kt * 128 + n * 16 + hi * 4);
    asm volatile("s_waitcnt vmcnt(0)" ::: "memory");
    __syncthreads();   // staged tile visible

#pragma unroll
    for (int sub = 0; sub < 2; ++sub) {
      // S^T = K @ Q^T + maskl (C-init): lane holds keys (16n+4hi+r), q = fr
      f32x4 s[4];
#pragma unroll
      for (int n = 0; n < 4; ++n) s[n] = mk[sub * 4 + n];
      __builtin_amdgcn_s_setprio(1);
#pragma unroll
      for (int n = 0; n < 4; ++n) {
        const int krow = n * 16 + fr;
#pragma unroll
        for (int c = 0; c < 2; ++c) {
          const int col = (c * 32 + fo) ^ ((fr & 7) * 8);
          const short8 kf = *(const short8*)&Ks[sub][krow * 64 + col];
          s[n] = MFMA_BF16(kf, c ? qf1 : qf0, s[n], 0, 0, 0);
        }
      }
      __builtin_amdgcn_s_setprio(0);
      // P = exp2(S) directly (log2e folded into q and mask)
      unsigned pk[4][2];
#pragma unroll
      for (int n = 0; n < 4; ++n) {
        const float p0 = exp2_raw(s[n][0]);
        const float p1 = exp2_raw(s[n][1]);
        const float p2 = exp2_raw(s[n][2]);
        const float p3 = exp2_raw(s[n][3]);
        pk[n][0] = pack_bf2(p0, p1);
        pk[n][1] = pack_bf2(p2, p3);
      }
      // PV + row-sum: out^T[d][q] += V^T @ P ; lacc += 1 @ P
      __builtin_amdgcn_s_setprio(1);
#pragma unroll
      for (int c = 0; c < 2; ++c) {
        int4v pw = {(int)pk[2 * c][0], (int)pk[2 * c][1],
                    (int)pk[2 * c + 1][0], (int)pk[2 * c + 1][1]};
        union { int4v i; short8 s; } pf; pf.i = pw;
#pragma unroll
        for (int m = 0; m < 4; ++m) {
          const int row = m * 16 + fr;
          const int col = (c * 32 + fo) ^ ((fr & 7) * 8);
          const short8 vf = *(const short8*)&Vs[sub][row * 64 + col];
          oacc[m] = MFMA_BF16(vf, pf.s, oacc[m], 0, 0, 0);
        }
        lacc = MFMA_BF16(ones, pf.s, lacc, 0, 0, 0);
      }
      __builtin_amdgcn_s_setprio(0);
    }
  }
  const float inv = 1.f / lacc[0];
  const int q = q0 + w * 16 + fr;
  ushort_t* dst = ctx + ((size_t)b * LL + q) * DD + h * 64 + hi * 4;
#pragma unroll
  for (int m = 0; m < 4; ++m) {
    int2v val;
    val[0] = (int)pack_bf2(oacc[m][0] * inv, oacc[m][1] * inv);
    val[1] = (int)pack_bf2(oacc[m][2] * inv, oacc[m][3] * inv);
    *(int2v*)(dst + m * 16) = val;
  }
}

// ---------------- launch ----------------
extern "C" void kernel_launch(void* const* d_in, const int* in_sizes, int n_in,
                              void* d_out, int out_size, void* d_ws,
                              size_t ws_size, hipStream_t stream) {
  const float* x = (const float*)d_in[0];
  const float* pcos = (const float*)d_in[1];
  const float* psin = (const float*)d_in[2];
  const float* mask = (const float*)d_in[3];
  const float* Wq = (const float*)d_in[4];
  const float* Wk = (const float*)d_in[5];
  const float* Wv = (const float*)d_in[6];
  const float* Wo = (const float*)d_in[7];
  const float* W1 = (const float*)d_in[8];
  const float* W2 = (const float*)d_in[9];
  const float* g1 = (const float*)d_in[10];
  const float* b1 = (const float*)d_in[11];
  const float* g2 = (const float*)d_in[12];
  const float* b2 = (const float*)d_in[13];
  float* out = (float*)d_out;
  char* ws = (char*)d_ws;

  // workspace layout (bytes)
  ushort_t* WQKVT = (ushort_t*)(ws);                        // 6 MB (3072x1024)
  ushort_t* WOT = (ushort_t*)(ws + 6291456);                // 2 MB
  ushort_t* W1T = (ushort_t*)(ws + 8388608);                // 4 MB (2048x1024, permuted)
  ushort_t* W2T = (ushort_t*)(ws + 12582912);               // 2 MB
  ushort_t* XN = (ushort_t*)(ws + 14680064);                // 16 MB
  float* MASKL = (float*)(ws + 31457280);                   // 32 KB
  ushort_t* GACT = (ushort_t*)(ws + 31457280 + 33554432);   // 16 MB
  ushort_t* QH = (ushort_t*)(ws + 81788928);                // 16 MB
  ushort_t* KH = (ushort_t*)(ws + 98566144);                // 16 MB
  ushort_t* VT = (ushort_t*)(ws + 115343360);               // 16 MB
  ushort_t* CTX = (ushort_t*)(ws + 132120576);              // 16 MB
  ushort_t* XMIDB = (ushort_t*)(ws + 148897792);            // 16 MB (bf16)

  // weights -> bf16 transposed (W1 with silu-pairing column permutation)
  wconv<0><<<dim3(32, 32), 256, 0, stream>>>(Wq, WQKVT, 1024, 1024);
  wconv<0><<<dim3(32, 32), 256, 0, stream>>>(Wk, WQKVT + 1024 * 1024, 1024, 1024);
  wconv<0><<<dim3(32, 32), 256, 0, stream>>>(Wv, WQKVT + 2 * 1024 * 1024, 1024, 1024);
  wconv<0><<<dim3(32, 32), 256, 0, stream>>>(Wo, WOT, 1024, 1024);
  wconv<1><<<dim3(64, 32), 256, 0, stream>>>(W1, W1T, 1024, 2048);
  wconv<0><<<dim3(32, 32), 256, 0, stream>>>(W2, W2T, 1024, 1024);
  mask_scale<<<(BB * LL) / 256, 256, 0, stream>>>(mask, MASKL);

  ln_kernel<0><<<NROW, 256, 0, stream>>>(x, g1, b1, XN);
  // QKV GEMM (BK=64) + fused rope/relayout (LDS-bounced, vectorized)
  gemm64<1><<<dim3(24, 64), 256, 0, stream>>>(
      XN, WQKVT, pcos, psin, QH, KH, VT, nullptr, nullptr, nullptr, nullptr,
      nullptr, NROW, 3072, 1024);
  attn_kernel<<<dim3(16, 64), 512, 0, stream>>>(QH, KH, VT, MASKL, CTX);
  // Wo GEMM (BK=64): XMIDB (bf16) = x + ctx @ Wo
  gemm64<3><<<dim3(8, 64), 256, 0, stream>>>(
      CTX, WOT, nullptr, nullptr, nullptr, nullptr, nullptr, nullptr, XMIDB,
      nullptr, x, nullptr, NROW, 1024, 1024);
  ln_kernel<1><<<NROW, 256, 0, stream>>>(XMIDB, g2, b2, XN);
  // W1 GEMM (BK=64) + fused silu gate
  gemm64<2><<<dim3(16, 64), 256, 0, stream>>>(
      XN, W1T, nullptr, nullptr, nullptr, nullptr, nullptr, GACT, nullptr,
      nullptr, nullptr, nullptr, NROW, 2048, 1024);
  // W2 GEMM (BK=64): out (fp32) = XMIDB + gact @ W2
  gemm64<4><<<dim3(8, 64), 256, 0, stream>>>(
      GACT, W2T, nullptr, nullptr, nullptr, nullptr, nullptr, nullptr, nullptr,
      out, nullptr, XMIDB, NROW, 1024, 1024);
}

// Round 16
// 333.503 us; speedup vs baseline: 1.0708x; 1.0708x over previous
//
#include <hip/hip_runtime.h>
#include <hip/hip_bf16.h>

typedef unsigned short ushort_t;
typedef short short8 __attribute__((ext_vector_type(8)));
typedef unsigned short u16x4 __attribute__((ext_vector_type(4)));
typedef float f32x4 __attribute__((ext_vector_type(4)));
typedef int int2v __attribute__((ext_vector_type(2)));
typedef int int4v __attribute__((ext_vector_type(4)));

#define MFMA_BF16 __builtin_amdgcn_mfma_f32_16x16x32_bf16

// global -> LDS async copy, 16B per lane. LDS base must be wave-uniform.
#define GLDS16(g, l) __builtin_amdgcn_global_load_lds( \
    (__attribute__((address_space(1))) void*)(g), \
    (__attribute__((address_space(3))) void*)(l), 16, 0, 0)

__device__ __forceinline__ unsigned short f2bf(float f) {
  union { float f; unsigned u; } v; v.f = f;
  unsigned r = v.u + 0x7FFFu + ((v.u >> 16) & 1u);
  return (unsigned short)(r >> 16);
}
__device__ __forceinline__ float bf2f(unsigned short h) {
  union { unsigned u; float f; } v; v.u = ((unsigned)h) << 16;
  return v.f;
}
__device__ __forceinline__ unsigned pack_bf2(float a, float b) {
  __hip_bfloat162 t = __float22bfloat162_rn(float2{a, b});
  union { __hip_bfloat162 h; unsigned u; } v; v.h = t;
  return v.u;
}
// raw 2^x (v_exp_f32)
__device__ __forceinline__ float exp2_raw(float x) {
  float r;
  asm volatile("v_exp_f32 %0, %1" : "=v"(r) : "v"(x));
  return r;
}

// ---------------- problem constants ----------------
#define BB 4
#define LL 2048
#define DD 1024
#define HH 16
#define HD 64
#define NROW (BB * LL)        // 8192
#define LOG2E 1.4426950408889634f

// ---------------- weight transpose-convert: W (RxC fp32) -> WT (CxR bf16) ---
// PERM=1 (W1 only): out-row permutation so x1 col j -> 64-block slot [0,32),
// x2 col j -> slot [32,64): silu gate pairs land in the same lane's acc.
template <int PERM>
__global__ __launch_bounds__(256) void wconv(const float* __restrict__ W,
                                             ushort_t* __restrict__ WT,
                                             int R, int C) {
  __shared__ float tile[32][33];
  const int ct = blockIdx.x * 32, rt = blockIdx.y * 32;
  const int tx = threadIdx.x & 31, ty = threadIdx.x >> 5; // ty 0..7
#pragma unroll
  for (int j = 0; j < 4; ++j)
    tile[ty + j * 8][tx] = W[(size_t)(rt + ty + j * 8) * C + ct + tx];
  __syncthreads();
  int orow0 = ct;
  if (PERM)
    orow0 = (ct < 1024) ? ((ct >> 5) * 64) : ((((ct - 1024) >> 5) * 64) + 32);
#pragma unroll
  for (int j = 0; j < 4; ++j)
    WT[(size_t)(orow0 + ty + j * 8) * R + rt + tx] = f2bf(tile[tx][ty + j * 8]);
}

// ---------------- mask pre-scale: maskl = mask * log2e ----------------
__global__ void mask_scale(const float* __restrict__ mask,
                           float* __restrict__ maskl) {
  const int i = blockIdx.x * 256 + threadIdx.x;
  maskl[i] = mask[i] * LOG2E;
}

// ---------------- layernorm: fp32/bf16 in -> bf16 out ----------------
// BIN=0 additionally writes a bf16 copy of the raw input to xb (if non-null)
// so downstream residual adds read 16MB instead of 32MB.
template <int BIN>
__global__ __launch_bounds__(256) void ln_kernel(const void* __restrict__ xin,
                                                 const float* __restrict__ g,
                                                 const float* __restrict__ bt,
                                                 ushort_t* __restrict__ out,
                                                 ushort_t* __restrict__ xb) {
  const int row = blockIdx.x, t = threadIdx.x;
  f32x4 v;
  if (BIN) {
    const u16x4 hv =
        *(const u16x4*)((const ushort_t*)xin + (size_t)row * DD + t * 4);
    v[0] = bf2f(hv[0]); v[1] = bf2f(hv[1]);
    v[2] = bf2f(hv[2]); v[3] = bf2f(hv[3]);
  } else {
    v = *(const f32x4*)((const float*)xin + (size_t)row * DD + t * 4);
    if (xb) {
      u16x4 xo;
      xo[0] = f2bf(v[0]); xo[1] = f2bf(v[1]);
      xo[2] = f2bf(v[2]); xo[3] = f2bf(v[3]);
      *(u16x4*)(xb + (size_t)row * DD + t * 4) = xo;
    }
  }
  float s = v[0] + v[1] + v[2] + v[3];
  float sq = v[0] * v[0] + v[1] * v[1] + v[2] * v[2] + v[3] * v[3];
#pragma unroll
  for (int off = 1; off < 64; off <<= 1) {
    s += __shfl_xor(s, off);
    sq += __shfl_xor(sq, off);
  }
  __shared__ float aw[4], aq[4];
  if ((t & 63) == 0) { aw[t >> 6] = s; aq[t >> 6] = sq; }
  __syncthreads();
  s = aw[0] + aw[1] + aw[2] + aw[3];
  sq = aq[0] + aq[1] + aq[2] + aq[3];
  const float mu = s * (1.f / DD);
  const float var = sq * (1.f / DD) - mu * mu;
  const float rs = rsqrtf(var + 1e-5f);
  u16x4 o;
#pragma unroll
  for (int j = 0; j < 4; ++j) {
    const int c = t * 4 + j;
    o[j] = f2bf((v[j] - mu) * rs * g[c] + bt[c]);
  }
  *(u16x4*)(out + (size_t)row * DD + t * 4) = o;
}

// ---------------- unified 128^2 GEMM, BK=64, swizzled LDS ------------------
// 2-D panel-grouped XCD swizzle. Per K-step: stage 16KB A + 16KB B, ONE
// vmcnt(0)+barrier drain, 2 k-half reg passes x 16 MFMA. XOR swizzle
// chunk^=(row&7) both sides.
// EPI 1: QKV -> rope(Q,K) (coalesced scalar-gather epilogue; q pre-scaled
//        0.125*log2e) + slot-permuted V.
// EPI 2: W1 (permuted cols) -> silu(x1)*x2 into gact.
// EPI 3: Wo -> bf16 out = bf16 resid + C.  EPI 4: W2 -> fp32 = bf16 resid + C.
template <int EPI>
__global__ __launch_bounds__(256) void gemm64(
    const ushort_t* __restrict__ A, const ushort_t* __restrict__ BT,
    const float* __restrict__ pcos, const float* __restrict__ psin,
    ushort_t* __restrict__ qh, ushort_t* __restrict__ kh,
    ushort_t* __restrict__ vt, ushort_t* __restrict__ gact,
    ushort_t* __restrict__ Cb, float* __restrict__ Cf,
    const ushort_t* __restrict__ residb,
    int M, int N, int K) {
  __shared__ ushort_t As[128 * 64];   // 16 KB
  __shared__ ushort_t Bs[128 * 64];   // 16 KB
  const int tid = threadIdx.x;
  const int lane = tid & 63;
  const int w = tid >> 6;             // 0..3
  const int wr = w >> 1, wc = w & 1;
  // 2-D panel-grouped XCD swizzle (bijective: M/128 = 64 = 8 XCD x 8 rows)
  const int orig = blockIdx.y * gridDim.x + blockIdx.x;
  const int xcd = orig & 7;
  const int lid = orig >> 3;
  const int bm = (xcd * 8 + (lid & 7)) * 128;
  const int bn = (lid >> 3) * 128;
  const int fr = lane & 15;
  const int hi = lane >> 4;           // 0..3
  const int srow8 = lane >> 3;                       // 0..7
  const int schunk = (lane & 7) ^ srow8;             // pre-swizzled src chunk
  f32x4 acc[4][4];
#pragma unroll
  for (int m = 0; m < 4; ++m)
#pragma unroll
    for (int n = 0; n < 4; ++n) acc[m][n] = (f32x4){0.f, 0.f, 0.f, 0.f};

  const int nk = K >> 6;
  for (int kt = 0; kt < nk; ++kt) {
    __syncthreads();  // previous step's ds_reads done
#pragma unroll
    for (int c = 0; c < 4; ++c) {
      const int rbase = w * 32 + c * 8;
      const int grow = rbase + srow8;
      GLDS16(A + (size_t)(bm + grow) * K + kt * 64 + schunk * 8,
             &As[rbase * 64]);
      GLDS16(BT + (size_t)(bn + grow) * K + kt * 64 + schunk * 8,
             &Bs[rbase * 64]);
    }
    asm volatile("s_waitcnt vmcnt(0)" ::: "memory");
    __syncthreads();  // staged tile visible
#pragma unroll
    for (int khf = 0; khf < 2; ++khf) {
      short8 af[4], bf_[4];
#pragma unroll
      for (int m = 0; m < 4; ++m) {
        const int r = wr * 64 + m * 16 + fr;
        af[m] = *(const short8*)&As[r * 64 + (((khf << 2) + hi) ^ (fr & 7)) * 8];
      }
#pragma unroll
      for (int n = 0; n < 4; ++n) {
        const int r = wc * 64 + n * 16 + fr;
        bf_[n] = *(const short8*)&Bs[r * 64 + (((khf << 2) + hi) ^ (fr & 7)) * 8];
      }
#pragma unroll
      for (int m = 0; m < 4; ++m)
#pragma unroll
        for (int n = 0; n < 4; ++n)
          acc[m][n] = MFMA_BF16(af[m], bf_[n], acc[m][n], 0, 0, 0);
    }
  }

  if (EPI == 1) {
    const int gcol = bn + wc * 64;       // 0..3071
    const int region = gcol >> 10;       // 0=q, 1=k, 2=v
    const int h = (gcol & 1023) >> 6;
    const int b = bm >> 11;
    if (region < 2) {
      // q pre-scaled by 1/8 * log2e so attn can use exp2 directly
      const float qs = (region == 0) ? (0.125f * LOG2E) : 1.0f;
      ushort_t* dstbuf = (region == 0) ? qh : kh;
      const int dbase = h * 64;
#pragma unroll
      for (int m = 0; m < 4; ++m) {
        const int gr0 = bm + wr * 64 + m * 16 + hi * 4;
#pragma unroll
        for (int r = 0; r < 4; ++r) {
          const int gr = gr0 + r;
          const int l = gr & 2047;
          const float* pcr = pcos + (size_t)gr * DD + dbase;
          const float* psr = psin + (size_t)gr * DD + dbase;
          ushort_t* dst = dstbuf + ((size_t)(b * HH + h) * LL + l) * HD;
#pragma unroll
          for (int n = 0; n < 2; ++n) {
            const int dlo = n * 16 + fr;
            const float xlo = acc[m][n][r], xhi = acc[m][n + 2][r];
            dst[dlo] = f2bf((xlo * pcr[dlo] - xhi * psr[dlo]) * qs);
            dst[dlo + 32] = f2bf((xhi * pcr[dlo + 32] + xlo * psr[dlo + 32]) * qs);
          }
        }
      }
    } else {
      // V: slot-permuted vt [B*H, HD, L]; key-in-tile = m*16 + 4*hi + r
      const size_t bhv = (size_t)(b * HH + h);
      const int l0 = (bm & 2047) + wr * 64;
      const int lt = l0 >> 6;
#pragma unroll
      for (int m = 0; m < 4; ++m) {
        const int slotb = 32 * (m >> 1) + 8 * hi + 4 * (m & 1);
#pragma unroll
        for (int n = 0; n < 4; ++n) {
          const int hd = n * 16 + fr;
          u16x4 wv;
          wv[0] = f2bf(acc[m][n][0]);
          wv[1] = f2bf(acc[m][n][1]);
          wv[2] = f2bf(acc[m][n][2]);
          wv[3] = f2bf(acc[m][n][3]);
          *(u16x4*)(vt + (bhv * HD + hd) * LL + lt * 64 + slotb) = wv;
        }
      }
    }
  } else if (EPI == 2) {
    // silu gate; wave's 64 permuted cols = 32 gate outputs
    const int jbase = ((bn + wc * 64) >> 6) * 32;
#pragma unroll
    for (int m = 0; m < 4; ++m) {
      const int gr0 = bm + wr * 64 + m * 16 + hi * 4;
#pragma unroll
      for (int r = 0; r < 4; ++r) {
        ushort_t* dst = gact + (size_t)(gr0 + r) * DD + jbase;
#pragma unroll
        for (int n = 0; n < 2; ++n) {
          const float x1 = acc[m][n][r];
          const float x2 = acc[m][n + 2][r];
          dst[n * 16 + fr] = f2bf(x1 / (1.f + __expf(-x1)) * x2);
        }
      }
    }
  } else {
#pragma unroll
    for (int m = 0; m < 4; ++m)
#pragma unroll
      for (int n = 0; n < 4; ++n)
#pragma unroll
        for (int r = 0; r < 4; ++r) {
          const int gr = bm + wr * 64 + m * 16 + hi * 4 + r;
          const int gc = bn + wc * 64 + n * 16 + fr;
          const size_t o = (size_t)gr * N + gc;
          if (EPI == 3) Cb[o] = f2bf(bf2f(residb[o]) + acc[m][n][r]);
          else          Cf[o] = bf2f(residb[o]) + acc[m][n][r];
        }
  }
}

// ---------------- flash attention (swapped QK^T, no-max softmax) -----------
// XCD-affinity remap: all 16 q-blocks of one head run on the SAME XCD
// (consecutively), so that head's 512KB K/V stays L2-resident. KVBLK=128
// single-buffer; P = exp2(S) (log2e pre-folded into q and mask).
__global__ __launch_bounds__(512) void attn_kernel(
    const ushort_t* __restrict__ qh, const ushort_t* __restrict__ kh,
    const ushort_t* __restrict__ vt, const float* __restrict__ maskl,
    ushort_t* __restrict__ ctx) {
  const int tid = threadIdx.x, lane = tid & 63, w = tid >> 6;  // w 0..7
  // XCD-affinity block remap (1024 blocks, 8 XCDs, 64 heads)
  const int flat = blockIdx.y * gridDim.x + blockIdx.x;
  const int xcd = flat & 7;
  const int slot = flat >> 3;              // 0..127
  const int bh = xcd * 8 + (slot >> 4);    // 8 heads per XCD
  const int q0 = (slot & 15) * 128;
  const int b = bh >> 4, h = bh & 15;
  __shared__ ushort_t Ks[2][64 * 64];   // [sub][kk][d], swizzled
  __shared__ ushort_t Vs[2][64 * 64];   // [sub][d][slot], swizzled
  const int fr = lane & 15;
  const int hi = lane >> 4;
  const int fo = hi * 8;
  const int qrow = q0 + w * 16 + fr;
  const size_t qoff = ((size_t)bh * LL + qrow) * HD + fo;
  const short8 qf0 = *(const short8*)(qh + qoff);
  const short8 qf1 = *(const short8*)(qh + qoff + 32);
  short8 ones;
#pragma unroll
  for (int i = 0; i < 8; ++i) ones[i] = (short)0x3F80;  // bf16 1.0

  f32x4 oacc[4];
  f32x4 lacc = (f32x4){0.f, 0.f, 0.f, 0.f};
#pragma unroll
  for (int m = 0; m < 4; ++m) oacc[m] = (f32x4){0.f, 0.f, 0.f, 0.f};

  const int lrow = lane >> 3;                    // row within 8-row seg
  const int lcs = ((lane & 7) ^ lrow) * 8;       // pre-swizzled source col
  const int rr = w * 8 + lrow;                   // 0..63

  const float* mrow = maskl + (size_t)b * LL;

  const int NT = LL / 128;                       // 16 iterations
  for (int kt = 0; kt < NT; ++kt) {
    __syncthreads();   // previous iteration's LDS reads done
    // stage 128 keys: 2 subtiles of K and V (4 loads per wave)
    GLDS16(kh + ((size_t)bh * LL + kt * 128 + rr) * HD + lcs, &Ks[0][w * 512]);
    GLDS16(kh + ((size_t)bh * LL + kt * 128 + 64 + rr) * HD + lcs,
           &Ks[1][w * 512]);
    GLDS16(vt + ((size_t)bh * HD + rr) * LL + kt * 128 + lcs, &Vs[0][w * 512]);
    GLDS16(vt + ((size_t)bh * HD + rr) * LL + kt * 128 + 64 + lcs,
           &Vs[1][w * 512]);
    // this tile's pre-scaled mask (L2-resident broadcast loads)
    f32x4 mk[8];
#pragma unroll
    for (int n = 0; n < 8; ++n)
      mk[n] = *(const f32x4*)(mrow + kt * 128 + n * 16 + hi * 4);
    asm volatile("s_waitcnt vmcnt(0)" ::: "memory");
    __syncthreads();   // staged tile visible

#pragma unroll
    for (int sub = 0; sub < 2; ++sub) {
      // S^T = K @ Q^T + maskl (C-init): lane holds keys (16n+4hi+r), q = fr
      f32x4 s[4];
#pragma unroll
      for (int n = 0; n < 4; ++n) s[n] = mk[sub * 4 + n];
      __builtin_amdgcn_s_setprio(1);
#pragma unroll
      for (int n = 0; n < 4; ++n) {
        const int krow = n * 16 + fr;
#pragma unroll
        for (int c = 0; c < 2; ++c) {
          const int col = (c * 32 + fo) ^ ((fr & 7) * 8);
          const short8 kf = *(const short8*)&Ks[sub][krow * 64 + col];
          s[n] = MFMA_BF16(kf, c ? qf1 : qf0, s[n], 0, 0, 0);
        }
      }
      __builtin_amdgcn_s_setprio(0);
      // P = exp2(S) directly (log2e folded into q and mask)
      unsigned pk[4][2];
#pragma unroll
      for (int n = 0; n < 4; ++n) {
        const float p0 = exp2_raw(s[n][0]);
        const float p1 = exp2_raw(s[n][1]);
        const float p2 = exp2_raw(s[n][2]);
        const float p3 = exp2_raw(s[n][3]);
        pk[n][0] = pack_bf2(p0, p1);
        pk[n][1] = pack_bf2(p2, p3);
      }
      // PV + row-sum: out^T[d][q] += V^T @ P ; lacc += 1 @ P
      __builtin_amdgcn_s_setprio(1);
#pragma unroll
      for (int c = 0; c < 2; ++c) {
        int4v pw = {(int)pk[2 * c][0], (int)pk[2 * c][1],
                    (int)pk[2 * c + 1][0], (int)pk[2 * c + 1][1]};
        union { int4v i; short8 s; } pf; pf.i = pw;
#pragma unroll
        for (int m = 0; m < 4; ++m) {
          const int row = m * 16 + fr;
          const int col = (c * 32 + fo) ^ ((fr & 7) * 8);
          const short8 vf = *(const short8*)&Vs[sub][row * 64 + col];
          oacc[m] = MFMA_BF16(vf, pf.s, oacc[m], 0, 0, 0);
        }
        lacc = MFMA_BF16(ones, pf.s, lacc, 0, 0, 0);
      }
      __builtin_amdgcn_s_setprio(0);
    }
  }
  const float inv = 1.f / lacc[0];
  const int q = q0 + w * 16 + fr;
  ushort_t* dst = ctx + ((size_t)b * LL + q) * DD + h * 64 + hi * 4;
#pragma unroll
  for (int m = 0; m < 4; ++m) {
    int2v val;
    val[0] = (int)pack_bf2(oacc[m][0] * inv, oacc[m][1] * inv);
    val[1] = (int)pack_bf2(oacc[m][2] * inv, oacc[m][3] * inv);
    *(int2v*)(dst + m * 16) = val;
  }
}

// ---------------- launch ----------------
extern "C" void kernel_launch(void* const* d_in, const int* in_sizes, int n_in,
                              void* d_out, int out_size, void* d_ws,
                              size_t ws_size, hipStream_t stream) {
  const float* x = (const float*)d_in[0];
  const float* pcos = (const float*)d_in[1];
  const float* psin = (const float*)d_in[2];
  const float* mask = (const float*)d_in[3];
  const float* Wq = (const float*)d_in[4];
  const float* Wk = (const float*)d_in[5];
  const float* Wv = (const float*)d_in[6];
  const float* Wo = (const float*)d_in[7];
  const float* W1 = (const float*)d_in[8];
  const float* W2 = (const float*)d_in[9];
  const float* g1 = (const float*)d_in[10];
  const float* b1 = (const float*)d_in[11];
  const float* g2 = (const float*)d_in[12];
  const float* b2 = (const float*)d_in[13];
  float* out = (float*)d_out;
  char* ws = (char*)d_ws;

  // workspace layout (bytes)
  ushort_t* WQKVT = (ushort_t*)(ws);                        // 6 MB (3072x1024)
  ushort_t* WOT = (ushort_t*)(ws + 6291456);                // 2 MB
  ushort_t* W1T = (ushort_t*)(ws + 8388608);                // 4 MB (2048x1024, permuted)
  ushort_t* W2T = (ushort_t*)(ws + 12582912);               // 2 MB
  ushort_t* XN = (ushort_t*)(ws + 14680064);                // 16 MB
  float* MASKL = (float*)(ws + 31457280);                   // 32 KB
  ushort_t* XB = (ushort_t*)(ws + 31457280 + 1048576);      // 16 MB (bf16 x)
  ushort_t* GACT = (ushort_t*)(ws + 31457280 + 33554432);   // 16 MB
  ushort_t* QH = (ushort_t*)(ws + 81788928);                // 16 MB
  ushort_t* KH = (ushort_t*)(ws + 98566144);                // 16 MB
  ushort_t* VT = (ushort_t*)(ws + 115343360);               // 16 MB
  ushort_t* CTX = (ushort_t*)(ws + 132120576);              // 16 MB
  ushort_t* XMIDB = (ushort_t*)(ws + 148897792);            // 16 MB (bf16)

  // weights -> bf16 transposed (W1 with silu-pairing column permutation)
  wconv<0><<<dim3(32, 32), 256, 0, stream>>>(Wq, WQKVT, 1024, 1024);
  wconv<0><<<dim3(32, 32), 256, 0, stream>>>(Wk, WQKVT + 1024 * 1024, 1024, 1024);
  wconv<0><<<dim3(32, 32), 256, 0, stream>>>(Wv, WQKVT + 2 * 1024 * 1024, 1024, 1024);
  wconv<0><<<dim3(32, 32), 256, 0, stream>>>(Wo, WOT, 1024, 1024);
  wconv<1><<<dim3(64, 32), 256, 0, stream>>>(W1, W1T, 1024, 2048);
  wconv<0><<<dim3(32, 32), 256, 0, stream>>>(W2, W2T, 1024, 1024);
  mask_scale<<<(BB * LL) / 256, 256, 0, stream>>>(mask, MASKL);

  // LN1 (+ bf16 copy of x for the Wo residual)
  ln_kernel<0><<<NROW, 256, 0, stream>>>(x, g1, b1, XN, XB);
  // QKV GEMM (BK=64) + fused rope/relayout
  gemm64<1><<<dim3(24, 64), 256, 0, stream>>>(
      XN, WQKVT, pcos, psin, QH, KH, VT, nullptr, nullptr, nullptr, nullptr,
      NROW, 3072, 1024);
  attn_kernel<<<dim3(16, 64), 512, 0, stream>>>(QH, KH, VT, MASKL, CTX);
  // Wo GEMM (BK=64): XMIDB (bf16) = xb + ctx @ Wo
  gemm64<3><<<dim3(8, 64), 256, 0, stream>>>(
      CTX, WOT, nullptr, nullptr, nullptr, nullptr, nullptr, nullptr, XMIDB,
      nullptr, XB, NROW, 1024, 1024);
  ln_kernel<1><<<NROW, 256, 0, stream>>>(XMIDB, g2, b2, XN, nullptr);
  // W1 GEMM (BK=64) + fused silu gate
  gemm64<2><<<dim3(16, 64), 256, 0, stream>>>(
      XN, W1T, nullptr, nullptr, nullptr, nullptr, nullptr, GACT, nullptr,
      nullptr, nullptr, NROW, 2048, 1024);
  // W2 GEMM (BK=64): out (fp32) = XMIDB + gact @ W2
  gemm64<4><<<dim3(8, 64), 256, 0, stream>>>(
      GACT, W2T, nullptr, nullptr, nullptr, nullptr, nullptr, nullptr, nullptr,
      out, XMIDB, NROW, 1024, 1024);
}

// Round 17
// 320.168 us; speedup vs baseline: 1.1154x; 1.0417x over previous
//
#include <hip/hip_runtime.h>
#include <hip/hip_bf16.h>

typedef unsigned short ushort_t;
typedef short short8 __attribute__((ext_vector_type(8)));
typedef unsigned short u16x4 __attribute__((ext_vector_type(4)));
typedef float f32x4 __attribute__((ext_vector_type(4)));
typedef int int2v __attribute__((ext_vector_type(2)));
typedef int int4v __attribute__((ext_vector_type(4)));

#define MFMA_BF16 __builtin_amdgcn_mfma_f32_16x16x32_bf16

// global -> LDS async copy, 16B per lane. LDS base must be wave-uniform.
#define GLDS16(g, l) __builtin_amdgcn_global_load_lds( \
    (__attribute__((address_space(1))) void*)(g), \
    (__attribute__((address_space(3))) void*)(l), 16, 0, 0)

__device__ __forceinline__ unsigned short f2bf(float f) {
  union { float f; unsigned u; } v; v.f = f;
  unsigned r = v.u + 0x7FFFu + ((v.u >> 16) & 1u);
  return (unsigned short)(r >> 16);
}
__device__ __forceinline__ float bf2f(unsigned short h) {
  union { unsigned u; float f; } v; v.u = ((unsigned)h) << 16;
  return v.f;
}
__device__ __forceinline__ unsigned pack_bf2(float a, float b) {
  __hip_bfloat162 t = __float22bfloat162_rn(float2{a, b});
  union { __hip_bfloat162 h; unsigned u; } v; v.h = t;
  return v.u;
}
// raw 2^x (v_exp_f32)
__device__ __forceinline__ float exp2_raw(float x) {
  float r;
  asm volatile("v_exp_f32 %0, %1" : "=v"(r) : "v"(x));
  return r;
}

// ---------------- problem constants ----------------
#define BB 4
#define LL 2048
#define DD 1024
#define HH 16
#define HD 64
#define NROW (BB * LL)        // 8192
#define LOG2E 1.4426950408889634f

// ---------------- weight transpose-convert: W (RxC fp32) -> WT (CxR bf16) ---
// PERM=1 (W1 only): out-row permutation so x1 col j -> 64-block slot [0,32),
// x2 col j -> slot [32,64): silu gate pairs land in the same lane's acc.
template <int PERM>
__global__ __launch_bounds__(256) void wconv(const float* __restrict__ W,
                                             ushort_t* __restrict__ WT,
                                             int R, int C) {
  __shared__ float tile[32][33];
  const int ct = blockIdx.x * 32, rt = blockIdx.y * 32;
  const int tx = threadIdx.x & 31, ty = threadIdx.x >> 5; // ty 0..7
#pragma unroll
  for (int j = 0; j < 4; ++j)
    tile[ty + j * 8][tx] = W[(size_t)(rt + ty + j * 8) * C + ct + tx];
  __syncthreads();
  int orow0 = ct;
  if (PERM)
    orow0 = (ct < 1024) ? ((ct >> 5) * 64) : ((((ct - 1024) >> 5) * 64) + 32);
#pragma unroll
  for (int j = 0; j < 4; ++j)
    WT[(size_t)(orow0 + ty + j * 8) * R + rt + tx] = f2bf(tile[tx][ty + j * 8]);
}

// ---------------- mask pre-scale: maskl = mask * log2e ----------------
__global__ void mask_scale(const float* __restrict__ mask,
                           float* __restrict__ maskl) {
  const int i = blockIdx.x * 256 + threadIdx.x;
  maskl[i] = mask[i] * LOG2E;
}

// ---------------- layernorm: fp32/bf16 in -> bf16 out ----------------
// BIN=0 additionally writes a bf16 copy of the raw input to xb (if non-null)
// so downstream residual adds read 16MB instead of 32MB.
template <int BIN>
__global__ __launch_bounds__(256) void ln_kernel(const void* __restrict__ xin,
                                                 const float* __restrict__ g,
                                                 const float* __restrict__ bt,
                                                 ushort_t* __restrict__ out,
                                                 ushort_t* __restrict__ xb) {
  const int row = blockIdx.x, t = threadIdx.x;
  f32x4 v;
  if (BIN) {
    const u16x4 hv =
        *(const u16x4*)((const ushort_t*)xin + (size_t)row * DD + t * 4);
    v[0] = bf2f(hv[0]); v[1] = bf2f(hv[1]);
    v[2] = bf2f(hv[2]); v[3] = bf2f(hv[3]);
  } else {
    v = *(const f32x4*)((const float*)xin + (size_t)row * DD + t * 4);
    if (xb) {
      u16x4 xo;
      xo[0] = f2bf(v[0]); xo[1] = f2bf(v[1]);
      xo[2] = f2bf(v[2]); xo[3] = f2bf(v[3]);
      *(u16x4*)(xb + (size_t)row * DD + t * 4) = xo;
    }
  }
  float s = v[0] + v[1] + v[2] + v[3];
  float sq = v[0] * v[0] + v[1] * v[1] + v[2] * v[2] + v[3] * v[3];
#pragma unroll
  for (int off = 1; off < 64; off <<= 1) {
    s += __shfl_xor(s, off);
    sq += __shfl_xor(sq, off);
  }
  __shared__ float aw[4], aq[4];
  if ((t & 63) == 0) { aw[t >> 6] = s; aq[t >> 6] = sq; }
  __syncthreads();
  s = aw[0] + aw[1] + aw[2] + aw[3];
  sq = aq[0] + aq[1] + aq[2] + aq[3];
  const float mu = s * (1.f / DD);
  const float var = sq * (1.f / DD) - mu * mu;
  const float rs = rsqrtf(var + 1e-5f);
  u16x4 o;
#pragma unroll
  for (int j = 0; j < 4; ++j) {
    const int c = t * 4 + j;
    o[j] = f2bf((v[j] - mu) * rs * g[c] + bt[c]);
  }
  *(u16x4*)(out + (size_t)row * DD + t * 4) = o;
}

// ---------------- unified 128^2 GEMM, BK=64, 1-deep prefetch ---------------
// Double-buffered LDS (2x32KB) with COUNTED vmcnt: stage tile t+1 into
// buf^1 BEFORE computing tile t; vmcnt(8) waits only for tile t's loads
// (issued one iteration earlier, latency hidden under compute+barriers).
// Barrier structure identical to the proven drain loop (2/step):
//   [stage(t+1); vmcnt(8); barrier A (t landed); compute(t); barrier B].
// Buf^1 overwrite is safe: its last readers finished before barrier B of
// step t-1. XOR swizzle chunk^=(row&7) on stage source AND ds_read.
// EPI 1: QKV -> rope(Q,K) (coalesced gathers; q pre-scaled 0.125*log2e)
//        + slot-permuted V.   EPI 2: W1 (permuted cols) -> silu gate.
// EPI 3: Wo -> bf16 = bf16 resid + C.  EPI 4: W2 -> fp32 = bf16 resid + C.
template <int EPI>
__global__ __launch_bounds__(256) void gemm64(
    const ushort_t* __restrict__ A, const ushort_t* __restrict__ BT,
    const float* __restrict__ pcos, const float* __restrict__ psin,
    ushort_t* __restrict__ qh, ushort_t* __restrict__ kh,
    ushort_t* __restrict__ vt, ushort_t* __restrict__ gact,
    ushort_t* __restrict__ Cb, float* __restrict__ Cf,
    const ushort_t* __restrict__ residb,
    int M, int N, int K) {
  __shared__ ushort_t As[2][128 * 64];   // 2 x 16 KB
  __shared__ ushort_t Bs[2][128 * 64];   // 2 x 16 KB
  const int tid = threadIdx.x;
  const int lane = tid & 63;
  const int w = tid >> 6;             // 0..3
  const int wr = w >> 1, wc = w & 1;
  // 2-D panel-grouped XCD swizzle (bijective: M/128 = 64 = 8 XCD x 8 rows)
  const int orig = blockIdx.y * gridDim.x + blockIdx.x;
  const int xcd = orig & 7;
  const int lid = orig >> 3;
  const int bm = (xcd * 8 + (lid & 7)) * 128;
  const int bn = (lid >> 3) * 128;
  const int fr = lane & 15;
  const int hi = lane >> 4;           // 0..3
  const int srow8 = lane >> 3;                       // 0..7
  const int schunk = (lane & 7) ^ srow8;             // pre-swizzled src chunk
  f32x4 acc[4][4];
#pragma unroll
  for (int m = 0; m < 4; ++m)
#pragma unroll
    for (int n = 0; n < 4; ++n) acc[m][n] = (f32x4){0.f, 0.f, 0.f, 0.f};

#define STAGE64(kt, bb)                                                      \
  {                                                                          \
    _Pragma("unroll") for (int c = 0; c < 4; ++c) {                          \
      const int rbase = w * 32 + c * 8;                                      \
      const int grow = rbase + srow8;                                        \
      GLDS16(A + (size_t)(bm + grow) * K + (kt) * 64 + schunk * 8,           \
             &As[bb][rbase * 64]);                                           \
      GLDS16(BT + (size_t)(bn + grow) * K + (kt) * 64 + schunk * 8,          \
             &Bs[bb][rbase * 64]);                                           \
    }                                                                        \
  }

  const int nk = K >> 6;
  STAGE64(0, 0);                       // 8 loads/wave in flight
#pragma unroll 1
  for (int kt = 0; kt < nk; ++kt) {
    const int cur = kt & 1;
    if (kt + 1 < nk) {
      STAGE64(kt + 1, cur ^ 1);        // +8 -> 16 in flight
      asm volatile("s_waitcnt vmcnt(8)" ::: "memory");  // tile kt landed
    } else {
      asm volatile("s_waitcnt vmcnt(0)" ::: "memory");
    }
    __syncthreads();                   // all waves' tile-kt loads landed
#pragma unroll
    for (int khf = 0; khf < 2; ++khf) {
      short8 af[4], bf_[4];
#pragma unroll
      for (int m = 0; m < 4; ++m) {
        const int r = wr * 64 + m * 16 + fr;
        af[m] =
            *(const short8*)&As[cur][r * 64 + (((khf << 2) + hi) ^ (fr & 7)) * 8];
      }
#pragma unroll
      for (int n = 0; n < 4; ++n) {
        const int r = wc * 64 + n * 16 + fr;
        bf_[n] =
            *(const short8*)&Bs[cur][r * 64 + (((khf << 2) + hi) ^ (fr & 7)) * 8];
      }
      __builtin_amdgcn_s_setprio(1);
#pragma unroll
      for (int m = 0; m < 4; ++m)
#pragma unroll
        for (int n = 0; n < 4; ++n)
          acc[m][n] = MFMA_BF16(af[m], bf_[n], acc[m][n], 0, 0, 0);
      __builtin_amdgcn_s_setprio(0);
    }
    __syncthreads();                   // all waves done reading buf[cur]
  }
#undef STAGE64

  if (EPI == 1) {
    const int gcol = bn + wc * 64;       // 0..3071
    const int region = gcol >> 10;       // 0=q, 1=k, 2=v
    const int h = (gcol & 1023) >> 6;
    const int b = bm >> 11;
    if (region < 2) {
      // q pre-scaled by 1/8 * log2e so attn can use exp2 directly
      const float qs = (region == 0) ? (0.125f * LOG2E) : 1.0f;
      ushort_t* dstbuf = (region == 0) ? qh : kh;
      const int dbase = h * 64;
#pragma unroll
      for (int m = 0; m < 4; ++m) {
        const int gr0 = bm + wr * 64 + m * 16 + hi * 4;
#pragma unroll
        for (int r = 0; r < 4; ++r) {
          const int gr = gr0 + r;
          const int l = gr & 2047;
          const float* pcr = pcos + (size_t)gr * DD + dbase;
          const float* psr = psin + (size_t)gr * DD + dbase;
          ushort_t* dst = dstbuf + ((size_t)(b * HH + h) * LL + l) * HD;
#pragma unroll
          for (int n = 0; n < 2; ++n) {
            const int dlo = n * 16 + fr;
            const float xlo = acc[m][n][r], xhi = acc[m][n + 2][r];
            dst[dlo] = f2bf((xlo * pcr[dlo] - xhi * psr[dlo]) * qs);
            dst[dlo + 32] = f2bf((xhi * pcr[dlo + 32] + xlo * psr[dlo + 32]) * qs);
          }
        }
      }
    } else {
      // V: slot-permuted vt [B*H, HD, L]; key-in-tile = m*16 + 4*hi + r
      const size_t bhv = (size_t)(b * HH + h);
      const int l0 = (bm & 2047) + wr * 64;
      const int lt = l0 >> 6;
#pragma unroll
      for (int m = 0; m < 4; ++m) {
        const int slotb = 32 * (m >> 1) + 8 * hi + 4 * (m & 1);
#pragma unroll
        for (int n = 0; n < 4; ++n) {
          const int hd = n * 16 + fr;
          u16x4 wv;
          wv[0] = f2bf(acc[m][n][0]);
          wv[1] = f2bf(acc[m][n][1]);
          wv[2] = f2bf(acc[m][n][2]);
          wv[3] = f2bf(acc[m][n][3]);
          *(u16x4*)(vt + (bhv * HD + hd) * LL + lt * 64 + slotb) = wv;
        }
      }
    }
  } else if (EPI == 2) {
    // silu gate; wave's 64 permuted cols = 32 gate outputs
    const int jbase = ((bn + wc * 64) >> 6) * 32;
#pragma unroll
    for (int m = 0; m < 4; ++m) {
      const int gr0 = bm + wr * 64 + m * 16 + hi * 4;
#pragma unroll
      for (int r = 0; r < 4; ++r) {
        ushort_t* dst = gact + (size_t)(gr0 + r) * DD + jbase;
#pragma unroll
        for (int n = 0; n < 2; ++n) {
          const float x1 = acc[m][n][r];
          const float x2 = acc[m][n + 2][r];
          dst[n * 16 + fr] = f2bf(x1 / (1.f + __expf(-x1)) * x2);
        }
      }
    }
  } else {
#pragma unroll
    for (int m = 0; m < 4; ++m)
#pragma unroll
      for (int n = 0; n < 4; ++n)
#pragma unroll
        for (int r = 0; r < 4; ++r) {
          const int gr = bm + wr * 64 + m * 16 + hi * 4 + r;
          const int gc = bn + wc * 64 + n * 16 + fr;
          const size_t o = (size_t)gr * N + gc;
          if (EPI == 3) Cb[o] = f2bf(bf2f(residb[o]) + acc[m][n][r]);
          else          Cf[o] = bf2f(residb[o]) + acc[m][n][r];
        }
  }
}

// ---------------- flash attention (swapped QK^T, no-max softmax) -----------
// XCD-affinity remap: all 16 q-blocks of one head run on the SAME XCD
// (consecutively), so that head's 512KB K/V stays L2-resident. KVBLK=128
// single-buffer; P = exp2(S) (log2e pre-folded into q and mask).
__global__ __launch_bounds__(512) void attn_kernel(
    const ushort_t* __restrict__ qh, const ushort_t* __restrict__ kh,
    const ushort_t* __restrict__ vt, const float* __restrict__ maskl,
    ushort_t* __restrict__ ctx) {
  const int tid = threadIdx.x, lane = tid & 63, w = tid >> 6;  // w 0..7
  // XCD-affinity block remap (1024 blocks, 8 XCDs, 64 heads)
  const int flat = blockIdx.y * gridDim.x + blockIdx.x;
  const int xcd = flat & 7;
  const int slot = flat >> 3;              // 0..127
  const int bh = xcd * 8 + (slot >> 4);    // 8 heads per XCD
  const int q0 = (slot & 15) * 128;
  const int b = bh >> 4, h = bh & 15;
  __shared__ ushort_t Ks[2][64 * 64];   // [sub][kk][d], swizzled
  __shared__ ushort_t Vs[2][64 * 64];   // [sub][d][slot], swizzled
  const int fr = lane & 15;
  const int hi = lane >> 4;
  const int fo = hi * 8;
  const int qrow = q0 + w * 16 + fr;
  const size_t qoff = ((size_t)bh * LL + qrow) * HD + fo;
  const short8 qf0 = *(const short8*)(qh + qoff);
  const short8 qf1 = *(const short8*)(qh + qoff + 32);
  short8 ones;
#pragma unroll
  for (int i = 0; i < 8; ++i) ones[i] = (short)0x3F80;  // bf16 1.0

  f32x4 oacc[4];
  f32x4 lacc = (f32x4){0.f, 0.f, 0.f, 0.f};
#pragma unroll
  for (int m = 0; m < 4; ++m) oacc[m] = (f32x4){0.f, 0.f, 0.f, 0.f};

  const int lrow = lane >> 3;                    // row within 8-row seg
  const int lcs = ((lane & 7) ^ lrow) * 8;       // pre-swizzled source col
  const int rr = w * 8 + lrow;                   // 0..63

  const float* mrow = maskl + (size_t)b * LL;

  const int NT = LL / 128;                       // 16 iterations
  for (int kt = 0; kt < NT; ++kt) {
    __syncthreads();   // previous iteration's LDS reads done
    // stage 128 keys: 2 subtiles of K and V (4 loads per wave)
    GLDS16(kh + ((size_t)bh * LL + kt * 128 + rr) * HD + lcs, &Ks[0][w * 512]);
    GLDS16(kh + ((size_t)bh * LL + kt * 128 + 64 + rr) * HD + lcs,
           &Ks[1][w * 512]);
    GLDS16(vt + ((size_t)bh * HD + rr) * LL + kt * 128 + lcs, &Vs[0][w * 512]);
    GLDS16(vt + ((size_t)bh * HD + rr) * LL + kt * 128 + 64 + lcs,
           &Vs[1][w * 512]);
    // this tile's pre-scaled mask (L2-resident broadcast loads)
    f32x4 mk[8];
#pragma unroll
    for (int n = 0; n < 8; ++n)
      mk[n] = *(const f32x4*)(mrow + kt * 128 + n * 16 + hi * 4);
    asm volatile("s_waitcnt vmcnt(0)" ::: "memory");
    __syncthreads();   // staged tile visible

#pragma unroll
    for (int sub = 0; sub < 2; ++sub) {
      // S^T = K @ Q^T + maskl (C-init): lane holds keys (16n+4hi+r), q = fr
      f32x4 s[4];
#pragma unroll
      for (int n = 0; n < 4; ++n) s[n] = mk[sub * 4 + n];
      __builtin_amdgcn_s_setprio(1);
#pragma unroll
      for (int n = 0; n < 4; ++n) {
        const int krow = n * 16 + fr;
#pragma unroll
        for (int c = 0; c < 2; ++c) {
          const int col = (c * 32 + fo) ^ ((fr & 7) * 8);
          const short8 kf = *(const short8*)&Ks[sub][krow * 64 + col];
          s[n] = MFMA_BF16(kf, c ? qf1 : qf0, s[n], 0, 0, 0);
        }
      }
      __builtin_amdgcn_s_setprio(0);
      // P = exp2(S) directly (log2e folded into q and mask)
      unsigned pk[4][2];
#pragma unroll
      for (int n = 0; n < 4; ++n) {
        const float p0 = exp2_raw(s[n][0]);
        const float p1 = exp2_raw(s[n][1]);
        const float p2 = exp2_raw(s[n][2]);
        const float p3 = exp2_raw(s[n][3]);
        pk[n][0] = pack_bf2(p0, p1);
        pk[n][1] = pack_bf2(p2, p3);
      }
      // PV + row-sum: out^T[d][q] += V^T @ P ; lacc += 1 @ P
      __builtin_amdgcn_s_setprio(1);
#pragma unroll
      for (int c = 0; c < 2; ++c) {
        int4v pw = {(int)pk[2 * c][0], (int)pk[2 * c][1],
                    (int)pk[2 * c + 1][0], (int)pk[2 * c + 1][1]};
        union { int4v i; short8 s; } pf; pf.i = pw;
#pragma unroll
        for (int m = 0; m < 4; ++m) {
          const int row = m * 16 + fr;
          const int col = (c * 32 + fo) ^ ((fr & 7) * 8);
          const short8 vf = *(const short8*)&Vs[sub][row * 64 + col];
          oacc[m] = MFMA_BF16(vf, pf.s, oacc[m], 0, 0, 0);
        }
        lacc = MFMA_BF16(ones, pf.s, lacc, 0, 0, 0);
      }
      __builtin_amdgcn_s_setprio(0);
    }
  }
  const float inv = 1.f / lacc[0];
  const int q = q0 + w * 16 + fr;
  ushort_t* dst = ctx + ((size_t)b * LL + q) * DD + h * 64 + hi * 4;
#pragma unroll
  for (int m = 0; m < 4; ++m) {
    int2v val;
    val[0] = (int)pack_bf2(oacc[m][0] * inv, oacc[m][1] * inv);
    val[1] = (int)pack_bf2(oacc[m][2] * inv, oacc[m][3] * inv);
    *(int2v*)(dst + m * 16) = val;
  }
}

// ---------------- launch ----------------
extern "C" void kernel_launch(void* const* d_in, const int* in_sizes, int n_in,
                              void* d_out, int out_size, void* d_ws,
                              size_t ws_size, hipStream_t stream) {
  const float* x = (const float*)d_in[0];
  const float* pcos = (const float*)d_in[1];
  const float* psin = (const float*)d_in[2];
  const float* mask = (const float*)d_in[3];
  const float* Wq = (const float*)d_in[4];
  const float* Wk = (const float*)d_in[5];
  const float* Wv = (const float*)d_in[6];
  const float* Wo = (const float*)d_in[7];
  const float* W1 = (const float*)d_in[8];
  const float* W2 = (const float*)d_in[9];
  const float* g1 = (const float*)d_in[10];
  const float* b1 = (const float*)d_in[11];
  const float* g2 = (const float*)d_in[12];
  const float* b2 = (const float*)d_in[13];
  float* out = (float*)d_out;
  char* ws = (char*)d_ws;

  // workspace layout (bytes)
  ushort_t* WQKVT = (ushort_t*)(ws);                        // 6 MB (3072x1024)
  ushort_t* WOT = (ushort_t*)(ws + 6291456);                // 2 MB
  ushort_t* W1T = (ushort_t*)(ws + 8388608);                // 4 MB (2048x1024, permuted)
  ushort_t* W2T = (ushort_t*)(ws + 12582912);               // 2 MB
  ushort_t* XN = (ushort_t*)(ws + 14680064);                // 16 MB
  float* MASKL = (float*)(ws + 31457280);                   // 32 KB
  ushort_t* XB = (ushort_t*)(ws + 31457280 + 1048576);      // 16 MB (bf16 x)
  ushort_t* GACT = (ushort_t*)(ws + 31457280 + 33554432);   // 16 MB
  ushort_t* QH = (ushort_t*)(ws + 81788928);                // 16 MB
  ushort_t* KH = (ushort_t*)(ws + 98566144);                // 16 MB
  ushort_t* VT = (ushort_t*)(ws + 115343360);               // 16 MB
  ushort_t* CTX = (ushort_t*)(ws + 132120576);              // 16 MB
  ushort_t* XMIDB = (ushort_t*)(ws + 148897792);            // 16 MB (bf16)

  // weights -> bf16 transposed (W1 with silu-pairing column permutation)
  wconv<0><<<dim3(32, 32), 256, 0, stream>>>(Wq, WQKVT, 1024, 1024);
  wconv<0><<<dim3(32, 32), 256, 0, stream>>>(Wk, WQKVT + 1024 * 1024, 1024, 1024);
  wconv<0><<<dim3(32, 32), 256, 0, stream>>>(Wv, WQKVT + 2 * 1024 * 1024, 1024, 1024);
  wconv<0><<<dim3(32, 32), 256, 0, stream>>>(Wo, WOT, 1024, 1024);
  wconv<1><<<dim3(64, 32), 256, 0, stream>>>(W1, W1T, 1024, 2048);
  wconv<0><<<dim3(32, 32), 256, 0, stream>>>(W2, W2T, 1024, 1024);
  mask_scale<<<(BB * LL) / 256, 256, 0, stream>>>(mask, MASKL);

  // LN1 (+ bf16 copy of x for the Wo residual)
  ln_kernel<0><<<NROW, 256, 0, stream>>>(x, g1, b1, XN, XB);
  // QKV GEMM (BK=64, prefetched) + fused rope/relayout
  gemm64<1><<<dim3(24, 64), 256, 0, stream>>>(
      XN, WQKVT, pcos, psin, QH, KH, VT, nullptr, nullptr, nullptr, nullptr,
      NROW, 3072, 1024);
  attn_kernel<<<dim3(16, 64), 512, 0, stream>>>(QH, KH, VT, MASKL, CTX);
  // Wo GEMM: XMIDB (bf16) = xb + ctx @ Wo
  gemm64<3><<<dim3(8, 64), 256, 0, stream>>>(
      CTX, WOT, nullptr, nullptr, nullptr, nullptr, nullptr, nullptr, XMIDB,
      nullptr, XB, NROW, 1024, 1024);
  ln_kernel<1><<<NROW, 256, 0, stream>>>(XMIDB, g2, b2, XN, nullptr);
  // W1 GEMM (prefetched) + fused silu gate
  gemm64<2><<<dim3(16, 64), 256, 0, stream>>>(
      XN, W1T, nullptr, nullptr, nullptr, nullptr, nullptr, GACT, nullptr,
      nullptr, nullptr, NROW, 2048, 1024);
  // W2 GEMM: out (fp32) = XMIDB + gact @ W2
  gemm64<4><<<dim3(8, 64), 256, 0, stream>>>(
      GACT, W2T, nullptr, nullptr, nullptr, nullptr, nullptr, nullptr, nullptr,
      out, XMIDB, NROW, 1024, 1024);
}